// Round 4
// baseline (468.193 us; speedup 1.0000x reference)
//
#include <hip/hip_runtime.h>
#include <cmath>

#define DIMN 8
#define SSTEPS 2048
#define MZ 64
#define TQN 1024
#define DS_F    4.8828125e-4f           // 1/2048
#define DT_F    1.0e-3f
#define SCALE_F 22.09708691207961f      // sqrt(ds)/dt
#define SQRTDT_F 0.031622776601683794f  // sqrt(dt)
#define LN2_F   0.6931471805599453f

typedef _Float16 f16x8 __attribute__((ext_vector_type(8)));
typedef float f32x4 __attribute__((ext_vector_type(4)));

__device__ __forceinline__ float sigmoidf_(float x) { return 1.f / (1.f + expf(-x)); }

// staging map: 16-lane phases cover 8 span-slots exactly 2x (conflict-free for
// row stride 40 halfs = 20 dwords); wave still touches the same global lines.
__device__ __forceinline__ void stage_idx(int idx, int& r, int& p)
{
    r = (idx & 7) | ((idx >> 5) << 3);
    p = (idx >> 3) & 3;
}

// ---------------- coef kernel: hurst -> {e=2h, c=rsqrt(2h ds)/Gamma(h+.5)} at t and t+dt ----
__global__ void coef_kernel(const float* __restrict__ t_in, const float* __restrict__ y0,
                            const float* __restrict__ W1, const float* __restrict__ b1,
                            const float* __restrict__ W2, const float* __restrict__ b2,
                            const float* __restrict__ Wc1, const float* __restrict__ bc1,
                            const float* __restrict__ Wc2, const float* __restrict__ bc2,
                            const float* __restrict__ dw, const float* __restrict__ cw,
                            float4* __restrict__ coef_t, float4* __restrict__ coef_z,
                            float* __restrict__ times_z)
{
    int gid = blockIdx.x * blockDim.x + threadIdx.x;
    if (gid >= TQN + MZ) return;
    bool isz = gid >= TQN;
    float tv;
    if (!isz) {
        tv = t_in[gid];
    } else {
        int j = gid - TQN;
        tv = 0.0055f + (float)j * (0.989f / 63.0f);   // linspace(t0+5.5dt, t1-5.5dt, 64)
        times_z[j] = tv;
    }
    float y = y0[0];
    float hc[10];
    #pragma unroll
    for (int j = 0; j < 10; ++j) hc[j] = tanhf(y * Wc1[j] + bc1[j]);
    float pc[DIMN];
    #pragma unroll
    for (int d = 0; d < DIMN; ++d) {
        float s = bc2[d];
        #pragma unroll
        for (int j = 0; j < 10; ++j) s += hc[j] * Wc2[d * 10 + j];
        pc[d] = sigmoidf_(s);
    }
    float dww = dw[0], cww = cw[0];
    float4 outv[DIMN];
    for (int which = 0; which < 2; ++which) {
        float tt = (which == 0) ? tv : tv + DT_F;
        float st = sinf(tt), ct = cosf(tt);
        float hid[10];
        #pragma unroll
        for (int j = 0; j < 10; ++j)
            hid[j] = tanhf(st * W1[j * 3 + 0] + ct * W1[j * 3 + 1] + tt * W1[j * 3 + 2] + b1[j]);
        #pragma unroll
        for (int d = 0; d < DIMN; ++d) {
            float s = b2[d];
            #pragma unroll
            for (int j = 0; j < 10; ++j) s += hid[j] * W2[d * 10 + j];
            float tc = sigmoidf_(s);
            float h = sigmoidf_(tc * dww + pc[d] * cww);
            float e = 2.f * h;
            float c = rsqrtf(e * DS_F) / tgammaf(h + 0.5f);
            if (which == 0) { outv[d].x = e; outv[d].y = c; }
            else            { outv[d].z = e; outv[d].w = c; }
        }
    }
    float4* dst = isz ? (coef_z + (size_t)(gid - TQN) * DIMN) : (coef_t + (size_t)gid * DIMN);
    #pragma unroll
    for (int d = 0; d < DIMN; ++d) dst[d] = outv[d];
}

// ---- strip of 8 weights, difference-form fast math (no catastrophic cancellation) ----------
__device__ __forceinline__ void side_weights(float tt, float e, float c, int sbase,
                                             float (&w)[8])
{
    float xprev = tt - (float)sbase * DS_F;
    float pa = 0.f;
    if (xprev > 0.f) pa = __builtin_amdgcn_exp2f(e * __builtin_amdgcn_logf(xprev));
    #pragma unroll
    for (int k = 1; k <= 8; ++k) {
        float xk = tt - (float)(sbase + k) * DS_F;
        float D, pan;
        if (xk > 0.f) {
            float om = xk * __builtin_amdgcn_rcpf(xprev);     // x_{k+1}/x_k in (0,1)
            float y2 = e * __builtin_amdgcn_logf(om);         // e*log2(om) <= 0
            float wl = y2 * LN2_F;                            // e*ln(om)
            float em = wl * (1.f + wl * (0.5f + wl * (0.16666667f + wl * (0.041666668f + wl * 0.008333334f))));
            float g = -em;
            if (wl < -0.3f) g = 1.f - __builtin_amdgcn_exp2f(y2);
            D = pa * g;
            pan = pa - D;
        } else {
            D = pa;
            pan = 0.f;
        }
        w[k - 1] = __builtin_amdgcn_sqrtf(D + 1e-12f) * c;
        pa = pan;
        xprev = xk;
    }
}

__device__ __forceinline__ unsigned pack_hl(float v)
{
    _Float16 h = (_Float16)v;
    _Float16 l = (_Float16)(v - (float)h);
    unsigned short hu = __builtin_bit_cast(unsigned short, h);
    unsigned short lu = __builtin_bit_cast(unsigned short, l);
    return (unsigned)hu | ((unsigned)lu << 16);
}

// ---------------- kmat_t: K(t) -> fp16 hi/lo split, transposed [d][t][s] -------------------
__global__ __launch_bounds__(256) void kmat_t_kernel(const float* __restrict__ times,
                                                     const float4* __restrict__ coef,
                                                     _Float16* __restrict__ KThi,
                                                     _Float16* __restrict__ KTlo)
{
    int tid = threadIdx.x;
    int txx = tid & 31, sidx = tid >> 5;
    int t = blockIdx.x * 32 + txx;
    int sbase = blockIdx.y * 64 + sidx * 8;
    int d = blockIdx.z;
    __shared__ unsigned shhl[32][65];
    float tq = times[t];
    float4 cf = coef[(size_t)t * DIMN + d];
    float wa[8], wb[8];
    side_weights(tq,        cf.x, cf.y, sbase, wa);
    side_weights(tq + DT_F, cf.z, cf.w, sbase, wb);
    #pragma unroll
    for (int k = 0; k < 8; ++k) {
        float v = fmaxf(wb[k] - wa[k], 0.f) * SCALE_F;
        shhl[txx][sidx * 8 + k] = pack_hl(v);
    }
    __syncthreads();
    int tl = tid >> 3, sc = tid & 7;
    unsigned dwv[8];
    #pragma unroll
    for (int j = 0; j < 8; ++j) dwv[j] = shhl[tl][sc * 8 + j];
    uint4 hv, lv;
    hv.x = __builtin_amdgcn_perm(dwv[1], dwv[0], 0x05040100u);
    hv.y = __builtin_amdgcn_perm(dwv[3], dwv[2], 0x05040100u);
    hv.z = __builtin_amdgcn_perm(dwv[5], dwv[4], 0x05040100u);
    hv.w = __builtin_amdgcn_perm(dwv[7], dwv[6], 0x05040100u);
    lv.x = __builtin_amdgcn_perm(dwv[1], dwv[0], 0x07060302u);
    lv.y = __builtin_amdgcn_perm(dwv[3], dwv[2], 0x07060302u);
    lv.z = __builtin_amdgcn_perm(dwv[5], dwv[4], 0x07060302u);
    lv.w = __builtin_amdgcn_perm(dwv[7], dwv[6], 0x07060302u);
    size_t o = ((size_t)(d * 1024) + blockIdx.x * 32 + tl) * 2048 + blockIdx.y * 64 + sc * 8;
    *(uint4*)&KThi[o] = hv;
    *(uint4*)&KTlo[o] = lv;
}

// ---------------- kmat_z: fp32 [d][s][m] AND fp16 split transposed [d][m][s] ---------------
__global__ __launch_bounds__(256) void kmat_z_kernel(const float* __restrict__ times,
                                                     const float4* __restrict__ coef,
                                                     float* __restrict__ Kz,
                                                     _Float16* __restrict__ KzThi,
                                                     _Float16* __restrict__ KzTlo)
{
    int tid = threadIdx.x;
    int txx = tid & 31, sidx = tid >> 5;
    int m = blockIdx.x * 32 + txx;
    int sbase = blockIdx.y * 64 + sidx * 8;
    int d = blockIdx.z;
    __shared__ unsigned shhl[32][65];
    float tq = times[m];
    float4 cf = coef[(size_t)m * DIMN + d];
    float wa[8], wb[8];
    side_weights(tq,        cf.x, cf.y, sbase, wa);
    side_weights(tq + DT_F, cf.z, cf.w, sbase, wb);
    #pragma unroll
    for (int k = 0; k < 8; ++k) {
        float v = fmaxf(wb[k] - wa[k], 0.f) * SCALE_F;
        Kz[((size_t)d * SSTEPS + sbase + k) * 64 + m] = v;
        shhl[txx][sidx * 8 + k] = pack_hl(v);
    }
    __syncthreads();
    int tl = tid >> 3, sc = tid & 7;
    unsigned dwv[8];
    #pragma unroll
    for (int j = 0; j < 8; ++j) dwv[j] = shhl[tl][sc * 8 + j];
    uint4 hv, lv;
    hv.x = __builtin_amdgcn_perm(dwv[1], dwv[0], 0x05040100u);
    hv.y = __builtin_amdgcn_perm(dwv[3], dwv[2], 0x05040100u);
    hv.z = __builtin_amdgcn_perm(dwv[5], dwv[4], 0x05040100u);
    hv.w = __builtin_amdgcn_perm(dwv[7], dwv[6], 0x05040100u);
    lv.x = __builtin_amdgcn_perm(dwv[1], dwv[0], 0x07060302u);
    lv.y = __builtin_amdgcn_perm(dwv[3], dwv[2], 0x07060302u);
    lv.z = __builtin_amdgcn_perm(dwv[5], dwv[4], 0x07060302u);
    lv.w = __builtin_amdgcn_perm(dwv[7], dwv[6], 0x07060302u);
    size_t o = ((size_t)(d * 64) + blockIdx.x * 32 + tl) * 2048 + blockIdx.y * 64 + sc * 8;
    *(uint4*)&KzThi[o] = hv;
    *(uint4*)&KzTlo[o] = lv;
}

// ---------------- Kzz partials: Kz^T Kz per dim, k-split 8 ---------------------------------
__global__ __launch_bounds__(256) void kzz_partial_kernel(const float* __restrict__ Kz,
                                                          float* __restrict__ part)
{
    int kidx = blockIdx.x;           // 0..7 (256 s each)
    int d = blockIdx.y;
    int tid = threadIdx.x, tx = tid & 15, ty = tid >> 4;
    __shared__ float As[32][64];
    float acc[4][4] = {};
    const float* base = Kz + ((size_t)d * SSTEPS + (size_t)kidx * 256) * 64;
    for (int c = 0; c < 8; ++c) {
        __syncthreads();
        #pragma unroll
        for (int l = 0; l < 2; ++l) {
            int idx = tid + l * 256;               // 512 float4
            int r = idx >> 4, c4 = idx & 15;
            *(float4*)&As[r][c4 * 4] = *(const float4*)(base + (size_t)(c * 32 + r) * 64 + c4 * 4);
        }
        __syncthreads();
        #pragma unroll
        for (int k = 0; k < 32; ++k) {
            float av[4], bv[4];
            *(float4*)&av[0] = *(float4*)&As[k][ty * 4];
            *(float4*)&bv[0] = *(float4*)&As[k][tx * 4];
            #pragma unroll
            for (int i = 0; i < 4; ++i)
                #pragma unroll
                for (int j = 0; j < 4; ++j) acc[i][j] += av[i] * bv[j];
        }
    }
    float* dst = part + (size_t)(kidx * DIMN + d) * 4096;
    #pragma unroll
    for (int i = 0; i < 4; ++i)
        *(float4*)&dst[(size_t)(ty * 4 + i) * 64 + tx * 4] =
            make_float4(acc[i][0], acc[i][1], acc[i][2], acc[i][3]);
}

// ---------------- k-split reduce (Kzz only now) --------------------------------------------
__global__ void reduce_kernel(const float* __restrict__ in, float* __restrict__ out,
                              int n, int parts)
{
    int i = blockIdx.x * 256 + threadIdx.x;
    if (i >= n) return;
    float s = 0.f;
    for (int p = 0; p < parts; ++p) s += in[(size_t)p * n + i];
    out[i] = s;
}

// ---------------- Cholesky (64x64 per dim) + delta_Bz --------------------------------------
__global__ __launch_bounds__(64) void chol_kernel(const float* __restrict__ Kzz,
                                                  const float* __restrict__ eps_z,
                                                  float* __restrict__ Lz, float* __restrict__ dBz)
{
    int d = blockIdx.x, i = threadIdx.x;
    __shared__ float A[64][65];
    for (int r = 0; r < 64; ++r)
        A[r][i] = Kzz[(size_t)d * 4096 + (size_t)r * 64 + i] + ((r == i) ? 1e-6f : 0.f);
    __syncthreads();
    for (int j = 0; j < 64; ++j) {
        float s = 0.f;
        if (i >= j) {
            s = A[i][j];
            for (int k = 0; k < j; ++k) s -= A[i][k] * A[j][k];
        }
        __syncthreads();
        if (i == j) A[j][j] = sqrtf(fmaxf(s, 1e-30f));
        __syncthreads();
        if (i > j) A[i][j] = s / A[j][j];
        __syncthreads();
    }
    for (int r = 0; r < 64; ++r)
        Lz[(size_t)d * 4096 + (size_t)r * 64 + i] = (i <= r) ? A[r][i] : 0.f;
    float s = 0.f;
    for (int k = 0; k <= i; ++k) s += A[i][k] * eps_z[d * 64 + k];
    dBz[d * 64 + i] = s;
}

// ---------------- Ktz partials via MFMA (fp16 3-pass split); d fastest (XCD locality) ------
__global__ __launch_bounds__(256) void ktz_mfma_kernel(const _Float16* __restrict__ KThi,
                                                       const _Float16* __restrict__ KTlo,
                                                       const _Float16* __restrict__ KzThi,
                                                       const _Float16* __restrict__ KzTlo,
                                                       float* __restrict__ part)
{
    int tid = threadIdx.x;
    int wave = tid >> 6, lane = tid & 63;
    int n = lane & 15, q = lane >> 4;
    int d = blockIdx.x;                 // fastest -> XCD k sees only d==k
    int t0 = blockIdx.y * 128;
    int split = blockIdx.z;
    int wr = (wave >> 1) * 64, wc = (wave & 1) * 32;

    __shared__ _Float16 Ah[128][40], Al[128][40];
    __shared__ _Float16 Bh[64][40],  Bl[64][40];

    f32x4 acc[4][2];
    #pragma unroll
    for (int i = 0; i < 4; ++i)
        #pragma unroll
        for (int j = 0; j < 2; ++j) acc[i][j] = (f32x4)0.f;

    const _Float16* ah = KThi + ((size_t)(d * 1024 + t0)) * 2048;
    const _Float16* al = KTlo + ((size_t)(d * 1024 + t0)) * 2048;
    const _Float16* bh = KzThi + ((size_t)(d * 64)) * 2048;
    const _Float16* bl = KzTlo + ((size_t)(d * 64)) * 2048;

    int s0end = split * 512 + 512;
    for (int s0 = split * 512; s0 < s0end; s0 += 32) {
        __syncthreads();
        #pragma unroll
        for (int l = 0; l < 2; ++l) {          // A: 512 pieces
            int r, p; stage_idx(tid + l * 256, r, p);
            *(float4*)&Ah[r][p * 8] = *(const float4*)(ah + (size_t)r * 2048 + s0 + p * 8);
            *(float4*)&Al[r][p * 8] = *(const float4*)(al + (size_t)r * 2048 + s0 + p * 8);
        }
        {                                       // B: 256 pieces
            int r, p; stage_idx(tid, r, p);
            *(float4*)&Bh[r][p * 8] = *(const float4*)(bh + (size_t)r * 2048 + s0 + p * 8);
            *(float4*)&Bl[r][p * 8] = *(const float4*)(bl + (size_t)r * 2048 + s0 + p * 8);
        }
        __syncthreads();
        f16x8 fAh[4], fAl[4], fBh[2], fBl[2];
        #pragma unroll
        for (int i = 0; i < 4; ++i) {
            fAh[i] = *(f16x8*)&Ah[wr + i * 16 + n][q * 8];
            fAl[i] = *(f16x8*)&Al[wr + i * 16 + n][q * 8];
        }
        #pragma unroll
        for (int j = 0; j < 2; ++j) {
            fBh[j] = *(f16x8*)&Bh[wc + j * 16 + n][q * 8];
            fBl[j] = *(f16x8*)&Bl[wc + j * 16 + n][q * 8];
        }
        #pragma unroll
        for (int i = 0; i < 4; ++i)
            #pragma unroll
            for (int j = 0; j < 2; ++j) {
                acc[i][j] = __builtin_amdgcn_mfma_f32_16x16x32_f16(fAh[i], fBh[j], acc[i][j], 0, 0, 0);
                acc[i][j] = __builtin_amdgcn_mfma_f32_16x16x32_f16(fAh[i], fBl[j], acc[i][j], 0, 0, 0);
                acc[i][j] = __builtin_amdgcn_mfma_f32_16x16x32_f16(fAl[i], fBh[j], acc[i][j], 0, 0, 0);
            }
    }
    float* dst = part + ((size_t)(split * DIMN + d)) * 1024 * 64;
    #pragma unroll
    for (int i = 0; i < 4; ++i)
        #pragma unroll
        for (int j = 0; j < 2; ++j)
            #pragma unroll
            for (int r = 0; r < 4; ++r) {
                int t = t0 + wr + i * 16 + q * 4 + r;
                dst[(size_t)t * 64 + wc + j * 16 + n] = acc[i][j][r];
            }
}

// ------ fused: sum Ktz partials + cho_solve + emit alpha splits + mean ---------------------
__global__ __launch_bounds__(64) void solve_kernel(const float* __restrict__ Lz,
                                                   const float* __restrict__ part2,
                                                   const float* __restrict__ dBz,
                                                   _Float16* __restrict__ aPhi,
                                                   _Float16* __restrict__ aPlo,
                                                   _Float16* __restrict__ aNhi,
                                                   _Float16* __restrict__ aNlo,
                                                   float* __restrict__ out0)
{
    int d = blockIdx.y;
    int t = blockIdx.x * 64 + threadIdx.x;
    __shared__ float L[64][65];
    __shared__ float inv[64];
    __shared__ float dB[64];
    for (int r = 0; r < 64; ++r)
        L[r][threadIdx.x] = Lz[(size_t)d * 4096 + (size_t)r * 64 + threadIdx.x];
    dB[threadIdx.x] = dBz[d * 64 + threadIdx.x];
    __syncthreads();
    inv[threadIdx.x] = 1.f / L[threadIdx.x][threadIdx.x];
    __syncthreads();
    float b[64];
    #pragma unroll
    for (int qq = 0; qq < 16; ++qq) {
        float4 a0 = *(const float4*)(part2 + ((size_t)(0 * 8 + d) * 1024 + t) * 64 + qq * 4);
        float4 a1 = *(const float4*)(part2 + ((size_t)(1 * 8 + d) * 1024 + t) * 64 + qq * 4);
        float4 a2 = *(const float4*)(part2 + ((size_t)(2 * 8 + d) * 1024 + t) * 64 + qq * 4);
        float4 a3 = *(const float4*)(part2 + ((size_t)(3 * 8 + d) * 1024 + t) * 64 + qq * 4);
        b[4 * qq]     = a0.x + a1.x + a2.x + a3.x;
        b[4 * qq + 1] = a0.y + a1.y + a2.y + a3.y;
        b[4 * qq + 2] = a0.z + a1.z + a2.z + a3.z;
        b[4 * qq + 3] = a0.w + a1.w + a2.w + a3.w;
    }
    #pragma unroll
    for (int j = 0; j < 64; ++j) {          // forward: L y = b
        float s = b[j];
        #pragma unroll
        for (int k = 0; k < j; ++k) s -= L[j][k] * b[k];
        b[j] = s * inv[j];
    }
    #pragma unroll
    for (int j = 63; j >= 0; --j) {         // backward: L^T x = y
        float s = b[j];
        #pragma unroll
        for (int k = j + 1; k < 64; ++k) s -= L[k][j] * b[k];
        b[j] = s * inv[j];
    }
    // mean = dot(alpha_col, dBz)
    float mn = 0.f;
    #pragma unroll
    for (int m = 0; m < 64; ++m) mn += b[m] * dB[m];
    out0[d * 1024 + t] = mn;
    // emit fp16 hi/lo splits, [d][t][m], +/- variants
    size_t o = ((size_t)(d * 1024 + t)) * 64;
    #pragma unroll
    for (int g = 0; g < 8; ++g) {
        union { _Float16 h[8]; float4 v; } ph, pl, nh, nl;
        #pragma unroll
        for (int k = 0; k < 8; ++k) {
            float x = b[g * 8 + k];
            _Float16 h = (_Float16)x;
            _Float16 lo = (_Float16)(x - (float)h);
            ph.h[k] = h;  pl.h[k] = lo;
            nh.h[k] = -h; nl.h[k] = -lo;
        }
        *(float4*)&aPhi[o + g * 8] = ph.v;
        *(float4*)&aPlo[o + g * 8] = pl.v;
        *(float4*)&aNhi[o + g * 8] = nh.v;
        *(float4*)&aNlo[o + g * 8] = nl.v;
    }
}

// ---------------- var/std via MFMA: Ktt - alpha^T alpha; d fastest (XCD locality) ----------
__global__ __launch_bounds__(256) void var_mfma_kernel(const _Float16* __restrict__ KThi,
                                                       const _Float16* __restrict__ KTlo,
                                                       const _Float16* __restrict__ aPhi,
                                                       const _Float16* __restrict__ aPlo,
                                                       const _Float16* __restrict__ aNhi,
                                                       const _Float16* __restrict__ aNlo,
                                                       float* __restrict__ out1)
{
    int tid = threadIdx.x;
    int wave = tid >> 6, lane = tid & 63;
    int n = lane & 15, q = lane >> 4;
    int d = blockIdx.x;                 // fastest -> XCD k sees only d==k
    int t0 = blockIdx.y * 128, u0 = blockIdx.z * 128;
    int wr = (wave >> 1) * 64, wc = (wave & 1) * 64;

    __shared__ _Float16 Ah[128][40], Al[128][40], Bh[128][40], Bl[128][40];

    f32x4 acc[4][4];
    #pragma unroll
    for (int i = 0; i < 4; ++i)
        #pragma unroll
        for (int j = 0; j < 4; ++j) acc[i][j] = (f32x4)0.f;

    for (int ck = 0; ck < 66; ++ck) {
        const _Float16 *pAh, *pAl, *pBh, *pBl;
        size_t astr;
        if (ck < 64) {
            size_t ao = ((size_t)(d * 1024 + t0)) * 2048 + ck * 32;
            size_t bo = ((size_t)(d * 1024 + u0)) * 2048 + ck * 32;
            pAh = KThi + ao; pAl = KTlo + ao;
            pBh = KThi + bo; pBl = KTlo + bo;
            astr = 2048;
        } else {
            size_t ao = ((size_t)(d * 1024 + t0)) * 64 + (ck - 64) * 32;
            size_t bo = ((size_t)(d * 1024 + u0)) * 64 + (ck - 64) * 32;
            pAh = aPhi + ao; pAl = aPlo + ao;
            pBh = aNhi + bo; pBl = aNlo + bo;
            astr = 64;
        }
        __syncthreads();
        #pragma unroll
        for (int l = 0; l < 2; ++l) {           // 512 pieces per tile
            int r, p; stage_idx(tid + l * 256, r, p);
            size_t go = (size_t)r * astr + p * 8;
            *(float4*)&Ah[r][p * 8] = *(const float4*)(pAh + go);
            *(float4*)&Al[r][p * 8] = *(const float4*)(pAl + go);
            *(float4*)&Bh[r][p * 8] = *(const float4*)(pBh + go);
            *(float4*)&Bl[r][p * 8] = *(const float4*)(pBl + go);
        }
        __syncthreads();
        f16x8 fAh[4], fAl[4], fBh[4], fBl[4];
        #pragma unroll
        for (int i = 0; i < 4; ++i) {
            fAh[i] = *(f16x8*)&Ah[wr + i * 16 + n][q * 8];
            fAl[i] = *(f16x8*)&Al[wr + i * 16 + n][q * 8];
            fBh[i] = *(f16x8*)&Bh[wc + i * 16 + n][q * 8];
            fBl[i] = *(f16x8*)&Bl[wc + i * 16 + n][q * 8];
        }
        #pragma unroll
        for (int i = 0; i < 4; ++i)
            #pragma unroll
            for (int j = 0; j < 4; ++j) {
                acc[i][j] = __builtin_amdgcn_mfma_f32_16x16x32_f16(fAh[i], fBh[j], acc[i][j], 0, 0, 0);
                acc[i][j] = __builtin_amdgcn_mfma_f32_16x16x32_f16(fAh[i], fBl[j], acc[i][j], 0, 0, 0);
                acc[i][j] = __builtin_amdgcn_mfma_f32_16x16x32_f16(fAl[i], fBh[j], acc[i][j], 0, 0, 0);
            }
    }
    float* dst = out1 + ((size_t)d << 20);
    #pragma unroll
    for (int i = 0; i < 4; ++i)
        #pragma unroll
        for (int j = 0; j < 4; ++j)
            #pragma unroll
            for (int r = 0; r < 4; ++r) {
                int t = t0 + wr + i * 16 + q * 4 + r;
                int u = u0 + wc + j * 16 + n;
                float v = acc[i][j][r];
                dst[(size_t)t * 1024 + u] = sqrtf(fmaxf(v, 1e-12f)) * SQRTDT_F;
            }
}

extern "C" void kernel_launch(void* const* d_in, const int* in_sizes, int n_in,
                              void* d_out, int out_size, void* d_ws, size_t ws_size,
                              hipStream_t stream)
{
    const float* t_in  = (const float*)d_in[0];
    const float* y0    = (const float*)d_in[1];
    const float* eps_z = (const float*)d_in[2];
    const float* W1    = (const float*)d_in[3];
    const float* b1    = (const float*)d_in[4];
    const float* W2    = (const float*)d_in[5];
    const float* b2    = (const float*)d_in[6];
    const float* Wc1   = (const float*)d_in[7];
    const float* bc1   = (const float*)d_in[8];
    const float* Wc2   = (const float*)d_in[9];
    const float* bc2   = (const float*)d_in[10];
    const float* dw    = (const float*)d_in[11];
    const float* cw    = (const float*)d_in[12];

    float* ws = (float*)d_ws;
    size_t off = 0;
    auto carve = [&](size_t n) { float* p = ws + off; off += n; return p; };
    float* coef_t   = carve(32768);
    float* coef_z   = carve(2048);
    float* times_z  = carve(64);
    float* Kzz      = carve(32768);
    float* Lz       = carve(32768);
    float* dBz      = carve(512);
    float* Kz       = carve(1048576);
    _Float16* KThi  = (_Float16*)carve(8388608);
    _Float16* KTlo  = (_Float16*)carve(8388608);
    _Float16* KzThi = (_Float16*)carve(524288);
    _Float16* KzTlo = (_Float16*)carve(524288);
    float* part1    = carve(262144);
    float* part2    = carve(2097152);
    _Float16* aPhi  = (_Float16*)carve(262144);
    _Float16* aPlo  = (_Float16*)carve(262144);
    _Float16* aNhi  = (_Float16*)carve(262144);
    _Float16* aNlo  = (_Float16*)carve(262144);

    float* out0 = (float*)d_out;
    float* out1 = out0 + (size_t)DIMN * 1024;

    coef_kernel<<<9, 128, 0, stream>>>(t_in, y0, W1, b1, W2, b2, Wc1, bc1, Wc2, bc2, dw, cw,
                                       (float4*)coef_t, (float4*)coef_z, times_z);
    kmat_t_kernel<<<dim3(32, 32, 8), 256, 0, stream>>>(t_in, (const float4*)coef_t,
                                                       KThi, KTlo);
    kmat_z_kernel<<<dim3(2, 32, 8), 256, 0, stream>>>(times_z, (const float4*)coef_z,
                                                      Kz, KzThi, KzTlo);
    kzz_partial_kernel<<<dim3(8, 8), 256, 0, stream>>>(Kz, part1);
    reduce_kernel<<<128, 256, 0, stream>>>(part1, Kzz, 32768, 8);
    chol_kernel<<<8, 64, 0, stream>>>(Kzz, eps_z, Lz, dBz);
    ktz_mfma_kernel<<<dim3(8, 8, 4), 256, 0, stream>>>(KThi, KTlo, KzThi, KzTlo, part2);
    solve_kernel<<<dim3(16, 8), 64, 0, stream>>>(Lz, part2, dBz, aPhi, aPlo, aNhi, aNlo, out0);
    var_mfma_kernel<<<dim3(8, 8, 8), 256, 0, stream>>>(KThi, KTlo, aPhi, aPlo, aNhi, aNlo, out1);
}

// Round 5
// 430.963 us; speedup vs baseline: 1.0864x; 1.0864x over previous
//
#include <hip/hip_runtime.h>
#include <cmath>

#define DIMN 8
#define SSTEPS 2048
#define MZ 64
#define TQN 1024
#define DS_F    4.8828125e-4f           // 1/2048
#define DT_F    1.0e-3f
#define SCALE_F 22.09708691207961f      // sqrt(ds)/dt
#define SQRTDT_F 0.031622776601683794f  // sqrt(dt)
#define LN2_F   0.6931471805599453f

typedef _Float16 f16x8 __attribute__((ext_vector_type(8)));
typedef float f32x4 __attribute__((ext_vector_type(4)));

__device__ __forceinline__ float sigmoidf_(float x) { return 1.f / (1.f + expf(-x)); }

// async global->LDS, 16B/lane; LDS dest = uniform base + lane*16 (wave-uniform base!)
__device__ __forceinline__ void gl_lds16(const _Float16* g, _Float16* l)
{
    __builtin_amdgcn_global_load_lds(
        (const __attribute__((address_space(1))) unsigned int*)g,
        (__attribute__((address_space(3))) unsigned int*)l, 16, 0, 0);
}

// ---------------- coef kernel: hurst -> {e=2h, c=rsqrt(2h ds)/Gamma(h+.5)} at t and t+dt ----
__global__ void coef_kernel(const float* __restrict__ t_in, const float* __restrict__ y0,
                            const float* __restrict__ W1, const float* __restrict__ b1,
                            const float* __restrict__ W2, const float* __restrict__ b2,
                            const float* __restrict__ Wc1, const float* __restrict__ bc1,
                            const float* __restrict__ Wc2, const float* __restrict__ bc2,
                            const float* __restrict__ dw, const float* __restrict__ cw,
                            float4* __restrict__ coef_t, float4* __restrict__ coef_z,
                            float* __restrict__ times_z)
{
    int gid = blockIdx.x * blockDim.x + threadIdx.x;
    if (gid >= TQN + MZ) return;
    bool isz = gid >= TQN;
    float tv;
    if (!isz) {
        tv = t_in[gid];
    } else {
        int j = gid - TQN;
        tv = 0.0055f + (float)j * (0.989f / 63.0f);   // linspace(t0+5.5dt, t1-5.5dt, 64)
        times_z[j] = tv;
    }
    float y = y0[0];
    float hc[10];
    #pragma unroll
    for (int j = 0; j < 10; ++j) hc[j] = tanhf(y * Wc1[j] + bc1[j]);
    float pc[DIMN];
    #pragma unroll
    for (int d = 0; d < DIMN; ++d) {
        float s = bc2[d];
        #pragma unroll
        for (int j = 0; j < 10; ++j) s += hc[j] * Wc2[d * 10 + j];
        pc[d] = sigmoidf_(s);
    }
    float dww = dw[0], cww = cw[0];
    float4 outv[DIMN];
    for (int which = 0; which < 2; ++which) {
        float tt = (which == 0) ? tv : tv + DT_F;
        float st = sinf(tt), ct = cosf(tt);
        float hid[10];
        #pragma unroll
        for (int j = 0; j < 10; ++j)
            hid[j] = tanhf(st * W1[j * 3 + 0] + ct * W1[j * 3 + 1] + tt * W1[j * 3 + 2] + b1[j]);
        #pragma unroll
        for (int d = 0; d < DIMN; ++d) {
            float s = b2[d];
            #pragma unroll
            for (int j = 0; j < 10; ++j) s += hid[j] * W2[d * 10 + j];
            float tc = sigmoidf_(s);
            float h = sigmoidf_(tc * dww + pc[d] * cww);
            float e = 2.f * h;
            float c = rsqrtf(e * DS_F) / tgammaf(h + 0.5f);
            if (which == 0) { outv[d].x = e; outv[d].y = c; }
            else            { outv[d].z = e; outv[d].w = c; }
        }
    }
    float4* dst = isz ? (coef_z + (size_t)(gid - TQN) * DIMN) : (coef_t + (size_t)gid * DIMN);
    #pragma unroll
    for (int d = 0; d < DIMN; ++d) dst[d] = outv[d];
}

// ---- strip of 8 weights, difference-form fast math (no catastrophic cancellation) ----------
__device__ __forceinline__ void side_weights(float tt, float e, float c, int sbase,
                                             float (&w)[8])
{
    float xprev = tt - (float)sbase * DS_F;
    float pa = 0.f;
    if (xprev > 0.f) pa = __builtin_amdgcn_exp2f(e * __builtin_amdgcn_logf(xprev));
    #pragma unroll
    for (int k = 1; k <= 8; ++k) {
        float xk = tt - (float)(sbase + k) * DS_F;
        float D, pan;
        if (xk > 0.f) {
            float om = xk * __builtin_amdgcn_rcpf(xprev);     // x_{k+1}/x_k in (0,1)
            float y2 = e * __builtin_amdgcn_logf(om);         // e*log2(om) <= 0
            float wl = y2 * LN2_F;                            // e*ln(om)
            float em = wl * (1.f + wl * (0.5f + wl * (0.16666667f + wl * (0.041666668f + wl * 0.008333334f))));
            float g = -em;
            if (wl < -0.3f) g = 1.f - __builtin_amdgcn_exp2f(y2);
            D = pa * g;
            pan = pa - D;
        } else {
            D = pa;
            pan = 0.f;
        }
        w[k - 1] = __builtin_amdgcn_sqrtf(D + 1e-12f) * c;
        pa = pan;
        xprev = xk;
    }
}

__device__ __forceinline__ unsigned pack_hl(float v)
{
    _Float16 h = (_Float16)v;
    _Float16 l = (_Float16)(v - (float)h);
    unsigned short hu = __builtin_bit_cast(unsigned short, h);
    unsigned short lu = __builtin_bit_cast(unsigned short, l);
    return (unsigned)hu | ((unsigned)lu << 16);
}

// ---------------- kmat_t: K(t) -> fp16 hi/lo split, transposed [d][t][s] -------------------
__global__ __launch_bounds__(256) void kmat_t_kernel(const float* __restrict__ times,
                                                     const float4* __restrict__ coef,
                                                     _Float16* __restrict__ KThi,
                                                     _Float16* __restrict__ KTlo)
{
    int tid = threadIdx.x;
    int txx = tid & 31, sidx = tid >> 5;
    int t = blockIdx.x * 32 + txx;
    int sbase = blockIdx.y * 64 + sidx * 8;
    int d = blockIdx.z;
    __shared__ unsigned shhl[32][65];
    float tq = times[t];
    float4 cf = coef[(size_t)t * DIMN + d];
    float wa[8], wb[8];
    side_weights(tq,        cf.x, cf.y, sbase, wa);
    side_weights(tq + DT_F, cf.z, cf.w, sbase, wb);
    #pragma unroll
    for (int k = 0; k < 8; ++k) {
        float v = fmaxf(wb[k] - wa[k], 0.f) * SCALE_F;
        shhl[txx][sidx * 8 + k] = pack_hl(v);
    }
    __syncthreads();
    int tl = tid >> 3, sc = tid & 7;
    unsigned dwv[8];
    #pragma unroll
    for (int j = 0; j < 8; ++j) dwv[j] = shhl[tl][sc * 8 + j];
    uint4 hv, lv;
    hv.x = __builtin_amdgcn_perm(dwv[1], dwv[0], 0x05040100u);
    hv.y = __builtin_amdgcn_perm(dwv[3], dwv[2], 0x05040100u);
    hv.z = __builtin_amdgcn_perm(dwv[5], dwv[4], 0x05040100u);
    hv.w = __builtin_amdgcn_perm(dwv[7], dwv[6], 0x05040100u);
    lv.x = __builtin_amdgcn_perm(dwv[1], dwv[0], 0x07060302u);
    lv.y = __builtin_amdgcn_perm(dwv[3], dwv[2], 0x07060302u);
    lv.z = __builtin_amdgcn_perm(dwv[5], dwv[4], 0x07060302u);
    lv.w = __builtin_amdgcn_perm(dwv[7], dwv[6], 0x07060302u);
    size_t o = ((size_t)(d * 1024) + blockIdx.x * 32 + tl) * 2048 + blockIdx.y * 64 + sc * 8;
    *(uint4*)&KThi[o] = hv;
    *(uint4*)&KTlo[o] = lv;
}

// ---------------- kmat_z: fp32 [d][s][m] AND fp16 split transposed [d][m][s] ---------------
__global__ __launch_bounds__(256) void kmat_z_kernel(const float* __restrict__ times,
                                                     const float4* __restrict__ coef,
                                                     float* __restrict__ Kz,
                                                     _Float16* __restrict__ KzThi,
                                                     _Float16* __restrict__ KzTlo)
{
    int tid = threadIdx.x;
    int txx = tid & 31, sidx = tid >> 5;
    int m = blockIdx.x * 32 + txx;
    int sbase = blockIdx.y * 64 + sidx * 8;
    int d = blockIdx.z;
    __shared__ unsigned shhl[32][65];
    float tq = times[m];
    float4 cf = coef[(size_t)m * DIMN + d];
    float wa[8], wb[8];
    side_weights(tq,        cf.x, cf.y, sbase, wa);
    side_weights(tq + DT_F, cf.z, cf.w, sbase, wb);
    #pragma unroll
    for (int k = 0; k < 8; ++k) {
        float v = fmaxf(wb[k] - wa[k], 0.f) * SCALE_F;
        Kz[((size_t)d * SSTEPS + sbase + k) * 64 + m] = v;
        shhl[txx][sidx * 8 + k] = pack_hl(v);
    }
    __syncthreads();
    int tl = tid >> 3, sc = tid & 7;
    unsigned dwv[8];
    #pragma unroll
    for (int j = 0; j < 8; ++j) dwv[j] = shhl[tl][sc * 8 + j];
    uint4 hv, lv;
    hv.x = __builtin_amdgcn_perm(dwv[1], dwv[0], 0x05040100u);
    hv.y = __builtin_amdgcn_perm(dwv[3], dwv[2], 0x05040100u);
    hv.z = __builtin_amdgcn_perm(dwv[5], dwv[4], 0x05040100u);
    hv.w = __builtin_amdgcn_perm(dwv[7], dwv[6], 0x05040100u);
    lv.x = __builtin_amdgcn_perm(dwv[1], dwv[0], 0x07060302u);
    lv.y = __builtin_amdgcn_perm(dwv[3], dwv[2], 0x07060302u);
    lv.z = __builtin_amdgcn_perm(dwv[5], dwv[4], 0x07060302u);
    lv.w = __builtin_amdgcn_perm(dwv[7], dwv[6], 0x07060302u);
    size_t o = ((size_t)(d * 64) + blockIdx.x * 32 + tl) * 2048 + blockIdx.y * 64 + sc * 8;
    *(uint4*)&KzThi[o] = hv;
    *(uint4*)&KzTlo[o] = lv;
}

// ---------------- Kzz partials: Kz^T Kz per dim, k-split 8 ---------------------------------
__global__ __launch_bounds__(256) void kzz_partial_kernel(const float* __restrict__ Kz,
                                                          float* __restrict__ part)
{
    int kidx = blockIdx.x;           // 0..7 (256 s each)
    int d = blockIdx.y;
    int tid = threadIdx.x, tx = tid & 15, ty = tid >> 4;
    __shared__ float As[32][64];
    float acc[4][4] = {};
    const float* base = Kz + ((size_t)d * SSTEPS + (size_t)kidx * 256) * 64;
    for (int c = 0; c < 8; ++c) {
        __syncthreads();
        #pragma unroll
        for (int l = 0; l < 2; ++l) {
            int idx = tid + l * 256;               // 512 float4
            int r = idx >> 4, c4 = idx & 15;
            *(float4*)&As[r][c4 * 4] = *(const float4*)(base + (size_t)(c * 32 + r) * 64 + c4 * 4);
        }
        __syncthreads();
        #pragma unroll
        for (int k = 0; k < 32; ++k) {
            float av[4], bv[4];
            *(float4*)&av[0] = *(float4*)&As[k][ty * 4];
            *(float4*)&bv[0] = *(float4*)&As[k][tx * 4];
            #pragma unroll
            for (int i = 0; i < 4; ++i)
                #pragma unroll
                for (int j = 0; j < 4; ++j) acc[i][j] += av[i] * bv[j];
        }
    }
    float* dst = part + (size_t)(kidx * DIMN + d) * 4096;
    #pragma unroll
    for (int i = 0; i < 4; ++i)
        *(float4*)&dst[(size_t)(ty * 4 + i) * 64 + tx * 4] =
            make_float4(acc[i][0], acc[i][1], acc[i][2], acc[i][3]);
}

// ---------------- k-split reduce (Kzz only) ------------------------------------------------
__global__ void reduce_kernel(const float* __restrict__ in, float* __restrict__ out,
                              int n, int parts)
{
    int i = blockIdx.x * 256 + threadIdx.x;
    if (i >= n) return;
    float s = 0.f;
    for (int p = 0; p < parts; ++p) s += in[(size_t)p * n + i];
    out[i] = s;
}

// ---------------- Cholesky (64x64 per dim) + delta_Bz --------------------------------------
__global__ __launch_bounds__(64) void chol_kernel(const float* __restrict__ Kzz,
                                                  const float* __restrict__ eps_z,
                                                  float* __restrict__ Lz, float* __restrict__ dBz)
{
    int d = blockIdx.x, i = threadIdx.x;
    __shared__ float A[64][65];
    for (int r = 0; r < 64; ++r)
        A[r][i] = Kzz[(size_t)d * 4096 + (size_t)r * 64 + i] + ((r == i) ? 1e-6f : 0.f);
    __syncthreads();
    for (int j = 0; j < 64; ++j) {
        float s = 0.f;
        if (i >= j) {
            s = A[i][j];
            for (int k = 0; k < j; ++k) s -= A[i][k] * A[j][k];
        }
        __syncthreads();
        if (i == j) A[j][j] = sqrtf(fmaxf(s, 1e-30f));
        __syncthreads();
        if (i > j) A[i][j] = s / A[j][j];
        __syncthreads();
    }
    for (int r = 0; r < 64; ++r)
        Lz[(size_t)d * 4096 + (size_t)r * 64 + i] = (i <= r) ? A[r][i] : 0.f;
    float s = 0.f;
    for (int k = 0; k <= i; ++k) s += A[i][k] * eps_z[d * 64 + k];
    dBz[d * 64 + i] = s;
}

// ---------------- Ktz partials via MFMA; global_load_lds + double buffer -------------------
__global__ __launch_bounds__(256, 2) void ktz_mfma_kernel(const _Float16* __restrict__ KThi,
                                                          const _Float16* __restrict__ KTlo,
                                                          const _Float16* __restrict__ KzThi,
                                                          const _Float16* __restrict__ KzTlo,
                                                          float* __restrict__ part)
{
    int tid = threadIdx.x;
    int wave = tid >> 6, lane = tid & 63;
    int n = lane & 15, q = lane >> 4;
    int lr = lane >> 2, lc = (lane & 3) * 8;
    int d = blockIdx.x;                 // fastest -> XCD locality
    int t0 = blockIdx.y * 128;
    int split = blockIdx.z;
    int wr = (wave >> 1) * 64, wc = (wave & 1) * 32;

    __shared__ _Float16 Ah[2][128][32], Al[2][128][32];
    __shared__ _Float16 Bh[2][64][32],  Bl[2][64][32];

    f32x4 acc[4][2];
    #pragma unroll
    for (int i = 0; i < 4; ++i)
        #pragma unroll
        for (int j = 0; j < 2; ++j) acc[i][j] = (f32x4)0.f;

    const size_t aRow = (size_t)(d * 1024 + t0);
    const size_t bRow = (size_t)(d * 64);
    int segA = wave * 32;               // 32 A rows per wave (2 instrs)
    int segB = wave * 16;               // 16 B rows per wave (1 instr)

    auto stage = [&](int buf, int c) {
        int s0 = split * 512 + c * 32;
        size_t ga = (aRow + segA + lr) * 2048 + s0 + lc;
        size_t gb = (bRow + segB + lr) * 2048 + s0 + lc;
        gl_lds16(KThi + ga,               &Ah[buf][segA][0]);
        gl_lds16(KThi + ga + 16 * 2048,   &Ah[buf][segA + 16][0]);
        gl_lds16(KTlo + ga,               &Al[buf][segA][0]);
        gl_lds16(KTlo + ga + 16 * 2048,   &Al[buf][segA + 16][0]);
        gl_lds16(KzThi + gb,              &Bh[buf][segB][0]);
        gl_lds16(KzTlo + gb,              &Bl[buf][segB][0]);
    };

    stage(0, 0);
    __syncthreads();
    for (int c = 0; c < 16; ++c) {
        int buf = c & 1;
        if (c + 1 < 16) stage(buf ^ 1, c + 1);
        f16x8 fAh[4], fAl[4], fBh[2], fBl[2];
        #pragma unroll
        for (int i = 0; i < 4; ++i) {
            fAh[i] = *(f16x8*)&Ah[buf][wr + i * 16 + n][q * 8];
            fAl[i] = *(f16x8*)&Al[buf][wr + i * 16 + n][q * 8];
        }
        #pragma unroll
        for (int j = 0; j < 2; ++j) {
            fBh[j] = *(f16x8*)&Bh[buf][wc + j * 16 + n][q * 8];
            fBl[j] = *(f16x8*)&Bl[buf][wc + j * 16 + n][q * 8];
        }
        #pragma unroll
        for (int i = 0; i < 4; ++i)
            #pragma unroll
            for (int j = 0; j < 2; ++j) {
                acc[i][j] = __builtin_amdgcn_mfma_f32_16x16x32_f16(fAh[i], fBh[j], acc[i][j], 0, 0, 0);
                acc[i][j] = __builtin_amdgcn_mfma_f32_16x16x32_f16(fAh[i], fBl[j], acc[i][j], 0, 0, 0);
                acc[i][j] = __builtin_amdgcn_mfma_f32_16x16x32_f16(fAl[i], fBh[j], acc[i][j], 0, 0, 0);
            }
        __syncthreads();
    }
    float* dst = part + ((size_t)(split * DIMN + d)) * 1024 * 64;
    #pragma unroll
    for (int i = 0; i < 4; ++i)
        #pragma unroll
        for (int j = 0; j < 2; ++j)
            #pragma unroll
            for (int r = 0; r < 4; ++r) {
                int t = t0 + wr + i * 16 + q * 4 + r;
                dst[(size_t)t * 64 + wc + j * 16 + n] = acc[i][j][r];
            }
}

// ------ fused: sum Ktz partials + cho_solve + emit alpha splits + mean ---------------------
__global__ __launch_bounds__(64) void solve_kernel(const float* __restrict__ Lz,
                                                   const float* __restrict__ part2,
                                                   const float* __restrict__ dBz,
                                                   _Float16* __restrict__ aPhi,
                                                   _Float16* __restrict__ aPlo,
                                                   _Float16* __restrict__ aNhi,
                                                   _Float16* __restrict__ aNlo,
                                                   float* __restrict__ out0)
{
    int d = blockIdx.y;
    int t = blockIdx.x * 64 + threadIdx.x;
    __shared__ float L[64][65];
    __shared__ float inv[64];
    __shared__ float dB[64];
    for (int r = 0; r < 64; ++r)
        L[r][threadIdx.x] = Lz[(size_t)d * 4096 + (size_t)r * 64 + threadIdx.x];
    dB[threadIdx.x] = dBz[d * 64 + threadIdx.x];
    __syncthreads();
    inv[threadIdx.x] = 1.f / L[threadIdx.x][threadIdx.x];
    __syncthreads();
    float b[64];
    #pragma unroll
    for (int qq = 0; qq < 16; ++qq) {
        float4 a0 = *(const float4*)(part2 + ((size_t)(0 * 8 + d) * 1024 + t) * 64 + qq * 4);
        float4 a1 = *(const float4*)(part2 + ((size_t)(1 * 8 + d) * 1024 + t) * 64 + qq * 4);
        float4 a2 = *(const float4*)(part2 + ((size_t)(2 * 8 + d) * 1024 + t) * 64 + qq * 4);
        float4 a3 = *(const float4*)(part2 + ((size_t)(3 * 8 + d) * 1024 + t) * 64 + qq * 4);
        b[4 * qq]     = a0.x + a1.x + a2.x + a3.x;
        b[4 * qq + 1] = a0.y + a1.y + a2.y + a3.y;
        b[4 * qq + 2] = a0.z + a1.z + a2.z + a3.z;
        b[4 * qq + 3] = a0.w + a1.w + a2.w + a3.w;
    }
    #pragma unroll
    for (int j = 0; j < 64; ++j) {          // forward: L y = b
        float s = b[j];
        #pragma unroll
        for (int k = 0; k < j; ++k) s -= L[j][k] * b[k];
        b[j] = s * inv[j];
    }
    #pragma unroll
    for (int j = 63; j >= 0; --j) {         // backward: L^T x = y
        float s = b[j];
        #pragma unroll
        for (int k = j + 1; k < 64; ++k) s -= L[k][j] * b[k];
        b[j] = s * inv[j];
    }
    float mn = 0.f;
    #pragma unroll
    for (int m = 0; m < 64; ++m) mn += b[m] * dB[m];
    out0[d * 1024 + t] = mn;
    size_t o = ((size_t)(d * 1024 + t)) * 64;
    #pragma unroll
    for (int g = 0; g < 8; ++g) {
        union { _Float16 h[8]; float4 v; } ph, pl, nh, nl;
        #pragma unroll
        for (int k = 0; k < 8; ++k) {
            float x = b[g * 8 + k];
            _Float16 h = (_Float16)x;
            _Float16 lo = (_Float16)(x - (float)h);
            ph.h[k] = h;  pl.h[k] = lo;
            nh.h[k] = -h; nl.h[k] = -lo;
        }
        *(float4*)&aPhi[o + g * 8] = ph.v;
        *(float4*)&aPlo[o + g * 8] = pl.v;
        *(float4*)&aNhi[o + g * 8] = nh.v;
        *(float4*)&aNlo[o + g * 8] = nl.v;
    }
}

// ---------------- var/std via MFMA; global_load_lds + double buffer ------------------------
__global__ __launch_bounds__(256, 2) void var_mfma_kernel(const _Float16* __restrict__ KThi,
                                                          const _Float16* __restrict__ KTlo,
                                                          const _Float16* __restrict__ aPhi,
                                                          const _Float16* __restrict__ aPlo,
                                                          const _Float16* __restrict__ aNhi,
                                                          const _Float16* __restrict__ aNlo,
                                                          float* __restrict__ out1)
{
    int tid = threadIdx.x;
    int wave = tid >> 6, lane = tid & 63;
    int n = lane & 15, q = lane >> 4;
    int lr = lane >> 2, lc = (lane & 3) * 8;
    int d = blockIdx.x;                 // fastest -> XCD locality
    int t0 = blockIdx.y * 128, u0 = blockIdx.z * 128;
    int wr = (wave >> 1) * 64, wc = (wave & 1) * 64;

    __shared__ _Float16 Ah[2][128][32], Al[2][128][32], Bh[2][128][32], Bl[2][128][32]; // 64 KB

    f32x4 acc[4][4];
    #pragma unroll
    for (int i = 0; i < 4; ++i)
        #pragma unroll
        for (int j = 0; j < 4; ++j) acc[i][j] = (f32x4)0.f;

    const size_t aRow = (size_t)(d * 1024 + t0);
    const size_t bRow = (size_t)(d * 1024 + u0);
    int segA = wave * 32;               // 32 rows per wave per tile (2 instrs per plane)

    auto stage = [&](int buf, int ck) {
        const _Float16 *ph, *pl, *qh, *ql;
        size_t str; int col;
        if (ck < 64) { ph = KThi; pl = KTlo; qh = KThi; ql = KTlo; str = 2048; col = ck * 32; }
        else         { ph = aPhi; pl = aPlo; qh = aNhi; ql = aNlo; str = 64;  col = (ck - 64) * 32; }
        size_t ga = (aRow + segA + lr) * str + col + lc;
        size_t gb = (bRow + segA + lr) * str + col + lc;
        gl_lds16(ph + ga,            &Ah[buf][segA][0]);
        gl_lds16(ph + ga + 16 * str, &Ah[buf][segA + 16][0]);
        gl_lds16(pl + ga,            &Al[buf][segA][0]);
        gl_lds16(pl + ga + 16 * str, &Al[buf][segA + 16][0]);
        gl_lds16(qh + gb,            &Bh[buf][segA][0]);
        gl_lds16(qh + gb + 16 * str, &Bh[buf][segA + 16][0]);
        gl_lds16(ql + gb,            &Bl[buf][segA][0]);
        gl_lds16(ql + gb + 16 * str, &Bl[buf][segA + 16][0]);
    };

    stage(0, 0);
    __syncthreads();
    for (int ck = 0; ck < 66; ++ck) {
        int buf = ck & 1;
        if (ck + 1 < 66) stage(buf ^ 1, ck + 1);   // DMA next chunk; overlaps MFMA below
        f16x8 fAh[4], fAl[4], fBh[4], fBl[4];
        #pragma unroll
        for (int i = 0; i < 4; ++i) {
            fAh[i] = *(f16x8*)&Ah[buf][wr + i * 16 + n][q * 8];
            fAl[i] = *(f16x8*)&Al[buf][wr + i * 16 + n][q * 8];
            fBh[i] = *(f16x8*)&Bh[buf][wc + i * 16 + n][q * 8];
            fBl[i] = *(f16x8*)&Bl[buf][wc + i * 16 + n][q * 8];
        }
        #pragma unroll
        for (int i = 0; i < 4; ++i)
            #pragma unroll
            for (int j = 0; j < 4; ++j) {
                acc[i][j] = __builtin_amdgcn_mfma_f32_16x16x32_f16(fAh[i], fBh[j], acc[i][j], 0, 0, 0);
                acc[i][j] = __builtin_amdgcn_mfma_f32_16x16x32_f16(fAh[i], fBl[j], acc[i][j], 0, 0, 0);
                acc[i][j] = __builtin_amdgcn_mfma_f32_16x16x32_f16(fAl[i], fBh[j], acc[i][j], 0, 0, 0);
            }
        __syncthreads();   // orders buf reuse; vmcnt drain here overlaps the work above
    }
    float* dst = out1 + ((size_t)d << 20);
    #pragma unroll
    for (int i = 0; i < 4; ++i)
        #pragma unroll
        for (int j = 0; j < 4; ++j)
            #pragma unroll
            for (int r = 0; r < 4; ++r) {
                int t = t0 + wr + i * 16 + q * 4 + r;
                int u = u0 + wc + j * 16 + n;
                float v = acc[i][j][r];
                dst[(size_t)t * 1024 + u] = sqrtf(fmaxf(v, 1e-12f)) * SQRTDT_F;
            }
}

extern "C" void kernel_launch(void* const* d_in, const int* in_sizes, int n_in,
                              void* d_out, int out_size, void* d_ws, size_t ws_size,
                              hipStream_t stream)
{
    const float* t_in  = (const float*)d_in[0];
    const float* y0    = (const float*)d_in[1];
    const float* eps_z = (const float*)d_in[2];
    const float* W1    = (const float*)d_in[3];
    const float* b1    = (const float*)d_in[4];
    const float* W2    = (const float*)d_in[5];
    const float* b2    = (const float*)d_in[6];
    const float* Wc1   = (const float*)d_in[7];
    const float* bc1   = (const float*)d_in[8];
    const float* Wc2   = (const float*)d_in[9];
    const float* bc2   = (const float*)d_in[10];
    const float* dw    = (const float*)d_in[11];
    const float* cw    = (const float*)d_in[12];

    float* ws = (float*)d_ws;
    size_t off = 0;
    auto carve = [&](size_t n) { float* p = ws + off; off += n; return p; };
    float* coef_t   = carve(32768);
    float* coef_z   = carve(2048);
    float* times_z  = carve(64);
    float* Kzz      = carve(32768);
    float* Lz       = carve(32768);
    float* dBz      = carve(512);
    float* Kz       = carve(1048576);
    _Float16* KThi  = (_Float16*)carve(8388608);
    _Float16* KTlo  = (_Float16*)carve(8388608);
    _Float16* KzThi = (_Float16*)carve(524288);
    _Float16* KzTlo = (_Float16*)carve(524288);
    float* part1    = carve(262144);
    float* part2    = carve(2097152);
    _Float16* aPhi  = (_Float16*)carve(262144);
    _Float16* aPlo  = (_Float16*)carve(262144);
    _Float16* aNhi  = (_Float16*)carve(262144);
    _Float16* aNlo  = (_Float16*)carve(262144);

    float* out0 = (float*)d_out;
    float* out1 = out0 + (size_t)DIMN * 1024;

    coef_kernel<<<9, 128, 0, stream>>>(t_in, y0, W1, b1, W2, b2, Wc1, bc1, Wc2, bc2, dw, cw,
                                       (float4*)coef_t, (float4*)coef_z, times_z);
    kmat_t_kernel<<<dim3(32, 32, 8), 256, 0, stream>>>(t_in, (const float4*)coef_t,
                                                       KThi, KTlo);
    kmat_z_kernel<<<dim3(2, 32, 8), 256, 0, stream>>>(times_z, (const float4*)coef_z,
                                                      Kz, KzThi, KzTlo);
    kzz_partial_kernel<<<dim3(8, 8), 256, 0, stream>>>(Kz, part1);
    reduce_kernel<<<128, 256, 0, stream>>>(part1, Kzz, 32768, 8);
    chol_kernel<<<8, 64, 0, stream>>>(Kzz, eps_z, Lz, dBz);
    ktz_mfma_kernel<<<dim3(8, 8, 4), 256, 0, stream>>>(KThi, KTlo, KzThi, KzTlo, part2);
    solve_kernel<<<dim3(16, 8), 64, 0, stream>>>(Lz, part2, dBz, aPhi, aPlo, aNhi, aNlo, out0);
    var_mfma_kernel<<<dim3(8, 8, 8), 256, 0, stream>>>(KThi, KTlo, aPhi, aPlo, aNhi, aNlo, out1);
}

// Round 6
// 385.893 us; speedup vs baseline: 1.2133x; 1.1168x over previous
//
#include <hip/hip_runtime.h>
#include <cmath>

#define DIMN 8
#define SSTEPS 2048
#define MZ 64
#define TQN 1024
#define DS_F    4.8828125e-4f           // 1/2048
#define DT_F    1.0e-3f
#define SCALE_F 22.09708691207961f      // sqrt(ds)/dt
#define SQRTDT_F 0.031622776601683794f  // sqrt(dt)
#define LN2_F   0.6931471805599453f

typedef _Float16 f16x8 __attribute__((ext_vector_type(8)));
typedef float f32x4 __attribute__((ext_vector_type(4)));

__device__ __forceinline__ float sigmoidf_(float x) { return 1.f / (1.f + expf(-x)); }

// async global->LDS, 16B/lane; LDS dest = uniform base + lane*16 (wave-uniform base!)
__device__ __forceinline__ void gl_lds16(const _Float16* g, _Float16* l)
{
    __builtin_amdgcn_global_load_lds(
        (const __attribute__((address_space(1))) unsigned int*)g,
        (__attribute__((address_space(3))) unsigned int*)l, 16, 0, 0);
}

// ---------------- coef kernel: hurst -> {e=2h, c=rsqrt(2h ds)/Gamma(h+.5)} at t and t+dt ----
__global__ void coef_kernel(const float* __restrict__ t_in, const float* __restrict__ y0,
                            const float* __restrict__ W1, const float* __restrict__ b1,
                            const float* __restrict__ W2, const float* __restrict__ b2,
                            const float* __restrict__ Wc1, const float* __restrict__ bc1,
                            const float* __restrict__ Wc2, const float* __restrict__ bc2,
                            const float* __restrict__ dw, const float* __restrict__ cw,
                            float4* __restrict__ coef_t, float4* __restrict__ coef_z,
                            float* __restrict__ times_z)
{
    int gid = blockIdx.x * blockDim.x + threadIdx.x;
    if (gid >= TQN + MZ) return;
    bool isz = gid >= TQN;
    float tv;
    if (!isz) {
        tv = t_in[gid];
    } else {
        int j = gid - TQN;
        tv = 0.0055f + (float)j * (0.989f / 63.0f);   // linspace(t0+5.5dt, t1-5.5dt, 64)
        times_z[j] = tv;
    }
    float y = y0[0];
    float hc[10];
    #pragma unroll
    for (int j = 0; j < 10; ++j) hc[j] = tanhf(y * Wc1[j] + bc1[j]);
    float pc[DIMN];
    #pragma unroll
    for (int d = 0; d < DIMN; ++d) {
        float s = bc2[d];
        #pragma unroll
        for (int j = 0; j < 10; ++j) s += hc[j] * Wc2[d * 10 + j];
        pc[d] = sigmoidf_(s);
    }
    float dww = dw[0], cww = cw[0];
    float4 outv[DIMN];
    for (int which = 0; which < 2; ++which) {
        float tt = (which == 0) ? tv : tv + DT_F;
        float st = sinf(tt), ct = cosf(tt);
        float hid[10];
        #pragma unroll
        for (int j = 0; j < 10; ++j)
            hid[j] = tanhf(st * W1[j * 3 + 0] + ct * W1[j * 3 + 1] + tt * W1[j * 3 + 2] + b1[j]);
        #pragma unroll
        for (int d = 0; d < DIMN; ++d) {
            float s = b2[d];
            #pragma unroll
            for (int j = 0; j < 10; ++j) s += hid[j] * W2[d * 10 + j];
            float tc = sigmoidf_(s);
            float h = sigmoidf_(tc * dww + pc[d] * cww);
            float e = 2.f * h;
            float c = rsqrtf(e * DS_F) / tgammaf(h + 0.5f);
            if (which == 0) { outv[d].x = e; outv[d].y = c; }
            else            { outv[d].z = e; outv[d].w = c; }
        }
    }
    float4* dst = isz ? (coef_z + (size_t)(gid - TQN) * DIMN) : (coef_t + (size_t)gid * DIMN);
    #pragma unroll
    for (int d = 0; d < DIMN; ++d) dst[d] = outv[d];
}

// ---- strip of 8 weights, difference-form fast math (no catastrophic cancellation) ----------
__device__ __forceinline__ void side_weights(float tt, float e, float c, int sbase,
                                             float (&w)[8])
{
    float xprev = tt - (float)sbase * DS_F;
    float pa = 0.f;
    if (xprev > 0.f) pa = __builtin_amdgcn_exp2f(e * __builtin_amdgcn_logf(xprev));
    #pragma unroll
    for (int k = 1; k <= 8; ++k) {
        float xk = tt - (float)(sbase + k) * DS_F;
        float D, pan;
        if (xk > 0.f) {
            float om = xk * __builtin_amdgcn_rcpf(xprev);     // x_{k+1}/x_k in (0,1)
            float y2 = e * __builtin_amdgcn_logf(om);         // e*log2(om) <= 0
            float wl = y2 * LN2_F;                            // e*ln(om)
            float em = wl * (1.f + wl * (0.5f + wl * (0.16666667f + wl * (0.041666668f + wl * 0.008333334f))));
            float g = -em;
            if (wl < -0.3f) g = 1.f - __builtin_amdgcn_exp2f(y2);
            D = pa * g;
            pan = pa - D;
        } else {
            D = pa;
            pan = 0.f;
        }
        w[k - 1] = __builtin_amdgcn_sqrtf(D + 1e-12f) * c;
        pa = pan;
        xprev = xk;
    }
}

__device__ __forceinline__ unsigned pack_hl(float v)
{
    _Float16 h = (_Float16)v;
    _Float16 l = (_Float16)(v - (float)h);
    unsigned short hu = __builtin_bit_cast(unsigned short, h);
    unsigned short lu = __builtin_bit_cast(unsigned short, l);
    return (unsigned)hu | ((unsigned)lu << 16);
}

// ---------------- kmat_t: K(t) -> fp16 hi/lo split, transposed [d][t][s] -------------------
__global__ __launch_bounds__(256) void kmat_t_kernel(const float* __restrict__ times,
                                                     const float4* __restrict__ coef,
                                                     _Float16* __restrict__ KThi,
                                                     _Float16* __restrict__ KTlo)
{
    int tid = threadIdx.x;
    int txx = tid & 31, sidx = tid >> 5;
    int t = blockIdx.x * 32 + txx;
    int sbase = blockIdx.y * 64 + sidx * 8;
    int d = blockIdx.z;
    __shared__ unsigned shhl[32][65];
    float tq = times[t];
    float4 cf = coef[(size_t)t * DIMN + d];
    float wa[8], wb[8];
    side_weights(tq,        cf.x, cf.y, sbase, wa);
    side_weights(tq + DT_F, cf.z, cf.w, sbase, wb);
    #pragma unroll
    for (int k = 0; k < 8; ++k) {
        float v = fmaxf(wb[k] - wa[k], 0.f) * SCALE_F;
        shhl[txx][sidx * 8 + k] = pack_hl(v);
    }
    __syncthreads();
    int tl = tid >> 3, sc = tid & 7;
    unsigned dwv[8];
    #pragma unroll
    for (int j = 0; j < 8; ++j) dwv[j] = shhl[tl][sc * 8 + j];
    uint4 hv, lv;
    hv.x = __builtin_amdgcn_perm(dwv[1], dwv[0], 0x05040100u);
    hv.y = __builtin_amdgcn_perm(dwv[3], dwv[2], 0x05040100u);
    hv.z = __builtin_amdgcn_perm(dwv[5], dwv[4], 0x05040100u);
    hv.w = __builtin_amdgcn_perm(dwv[7], dwv[6], 0x05040100u);
    lv.x = __builtin_amdgcn_perm(dwv[1], dwv[0], 0x07060302u);
    lv.y = __builtin_amdgcn_perm(dwv[3], dwv[2], 0x07060302u);
    lv.z = __builtin_amdgcn_perm(dwv[5], dwv[4], 0x07060302u);
    lv.w = __builtin_amdgcn_perm(dwv[7], dwv[6], 0x07060302u);
    size_t o = ((size_t)(d * 1024) + blockIdx.x * 32 + tl) * 2048 + blockIdx.y * 64 + sc * 8;
    *(uint4*)&KThi[o] = hv;
    *(uint4*)&KTlo[o] = lv;
}

// ---------------- kmat_z: fp32 [d][s][m] AND fp16 split transposed [d][m][s] ---------------
__global__ __launch_bounds__(256) void kmat_z_kernel(const float* __restrict__ times,
                                                     const float4* __restrict__ coef,
                                                     float* __restrict__ Kz,
                                                     _Float16* __restrict__ KzThi,
                                                     _Float16* __restrict__ KzTlo)
{
    int tid = threadIdx.x;
    int txx = tid & 31, sidx = tid >> 5;
    int m = blockIdx.x * 32 + txx;
    int sbase = blockIdx.y * 64 + sidx * 8;
    int d = blockIdx.z;
    __shared__ unsigned shhl[32][65];
    float tq = times[m];
    float4 cf = coef[(size_t)m * DIMN + d];
    float wa[8], wb[8];
    side_weights(tq,        cf.x, cf.y, sbase, wa);
    side_weights(tq + DT_F, cf.z, cf.w, sbase, wb);
    #pragma unroll
    for (int k = 0; k < 8; ++k) {
        float v = fmaxf(wb[k] - wa[k], 0.f) * SCALE_F;
        Kz[((size_t)d * SSTEPS + sbase + k) * 64 + m] = v;
        shhl[txx][sidx * 8 + k] = pack_hl(v);
    }
    __syncthreads();
    int tl = tid >> 3, sc = tid & 7;
    unsigned dwv[8];
    #pragma unroll
    for (int j = 0; j < 8; ++j) dwv[j] = shhl[tl][sc * 8 + j];
    uint4 hv, lv;
    hv.x = __builtin_amdgcn_perm(dwv[1], dwv[0], 0x05040100u);
    hv.y = __builtin_amdgcn_perm(dwv[3], dwv[2], 0x05040100u);
    hv.z = __builtin_amdgcn_perm(dwv[5], dwv[4], 0x05040100u);
    hv.w = __builtin_amdgcn_perm(dwv[7], dwv[6], 0x05040100u);
    lv.x = __builtin_amdgcn_perm(dwv[1], dwv[0], 0x07060302u);
    lv.y = __builtin_amdgcn_perm(dwv[3], dwv[2], 0x07060302u);
    lv.z = __builtin_amdgcn_perm(dwv[5], dwv[4], 0x07060302u);
    lv.w = __builtin_amdgcn_perm(dwv[7], dwv[6], 0x07060302u);
    size_t o = ((size_t)(d * 64) + blockIdx.x * 32 + tl) * 2048 + blockIdx.y * 64 + sc * 8;
    *(uint4*)&KzThi[o] = hv;
    *(uint4*)&KzTlo[o] = lv;
}

// ---------------- Kzz partials: Kz^T Kz per dim, k-split 8 ---------------------------------
__global__ __launch_bounds__(256) void kzz_partial_kernel(const float* __restrict__ Kz,
                                                          float* __restrict__ part)
{
    int kidx = blockIdx.x;           // 0..7 (256 s each)
    int d = blockIdx.y;
    int tid = threadIdx.x, tx = tid & 15, ty = tid >> 4;
    __shared__ float As[32][64];
    float acc[4][4] = {};
    const float* base = Kz + ((size_t)d * SSTEPS + (size_t)kidx * 256) * 64;
    for (int c = 0; c < 8; ++c) {
        __syncthreads();
        #pragma unroll
        for (int l = 0; l < 2; ++l) {
            int idx = tid + l * 256;               // 512 float4
            int r = idx >> 4, c4 = idx & 15;
            *(float4*)&As[r][c4 * 4] = *(const float4*)(base + (size_t)(c * 32 + r) * 64 + c4 * 4);
        }
        __syncthreads();
        #pragma unroll
        for (int k = 0; k < 32; ++k) {
            float av[4], bv[4];
            *(float4*)&av[0] = *(float4*)&As[k][ty * 4];
            *(float4*)&bv[0] = *(float4*)&As[k][tx * 4];
            #pragma unroll
            for (int i = 0; i < 4; ++i)
                #pragma unroll
                for (int j = 0; j < 4; ++j) acc[i][j] += av[i] * bv[j];
        }
    }
    float* dst = part + (size_t)(kidx * DIMN + d) * 4096;
    #pragma unroll
    for (int i = 0; i < 4; ++i)
        *(float4*)&dst[(size_t)(ty * 4 + i) * 64 + tx * 4] =
            make_float4(acc[i][0], acc[i][1], acc[i][2], acc[i][3]);
}

// ---------------- k-split reduce (Kzz only) ------------------------------------------------
__global__ void reduce_kernel(const float* __restrict__ in, float* __restrict__ out,
                              int n, int parts)
{
    int i = blockIdx.x * 256 + threadIdx.x;
    if (i >= n) return;
    float s = 0.f;
    for (int p = 0; p < parts; ++p) s += in[(size_t)p * n + i];
    out[i] = s;
}

// ---------------- Cholesky (64x64 per dim) + delta_Bz --------------------------------------
__global__ __launch_bounds__(64) void chol_kernel(const float* __restrict__ Kzz,
                                                  const float* __restrict__ eps_z,
                                                  float* __restrict__ Lz, float* __restrict__ dBz)
{
    int d = blockIdx.x, i = threadIdx.x;
    __shared__ float A[64][65];
    for (int r = 0; r < 64; ++r)
        A[r][i] = Kzz[(size_t)d * 4096 + (size_t)r * 64 + i] + ((r == i) ? 1e-6f : 0.f);
    __syncthreads();
    for (int j = 0; j < 64; ++j) {
        float s = 0.f;
        if (i >= j) {
            s = A[i][j];
            for (int k = 0; k < j; ++k) s -= A[i][k] * A[j][k];
        }
        __syncthreads();
        if (i == j) A[j][j] = sqrtf(fmaxf(s, 1e-30f));
        __syncthreads();
        if (i > j) A[i][j] = s / A[j][j];
        __syncthreads();
    }
    for (int r = 0; r < 64; ++r)
        Lz[(size_t)d * 4096 + (size_t)r * 64 + i] = (i <= r) ? A[r][i] : 0.f;
    float s = 0.f;
    for (int k = 0; k <= i; ++k) s += A[i][k] * eps_z[d * 64 + k];
    dBz[d * 64 + i] = s;
}

// ---------------- Ktz partials via MFMA; global_load_lds + double buffer -------------------
__global__ __launch_bounds__(256, 2) void ktz_mfma_kernel(const _Float16* __restrict__ KThi,
                                                          const _Float16* __restrict__ KTlo,
                                                          const _Float16* __restrict__ KzThi,
                                                          const _Float16* __restrict__ KzTlo,
                                                          float* __restrict__ part)
{
    int tid = threadIdx.x;
    int wave = tid >> 6, lane = tid & 63;
    int n = lane & 15, q = lane >> 4;
    int lr = lane >> 2, lc = (lane & 3) * 8;
    int d = blockIdx.x;                 // fastest -> XCD locality
    int t0 = blockIdx.y * 128;
    int split = blockIdx.z;
    int wr = (wave >> 1) * 64, wc = (wave & 1) * 32;

    __shared__ _Float16 Ah[2][128][32], Al[2][128][32];
    __shared__ _Float16 Bh[2][64][32],  Bl[2][64][32];

    f32x4 acc[4][2];
    #pragma unroll
    for (int i = 0; i < 4; ++i)
        #pragma unroll
        for (int j = 0; j < 2; ++j) acc[i][j] = (f32x4)0.f;

    const size_t aRow = (size_t)(d * 1024 + t0);
    const size_t bRow = (size_t)(d * 64);
    int segA = wave * 32;               // 32 A rows per wave (2 instrs)
    int segB = wave * 16;               // 16 B rows per wave (1 instr)

    auto stage = [&](int buf, int c) {
        int s0 = split * 512 + c * 32;
        size_t ga = (aRow + segA + lr) * 2048 + s0 + lc;
        size_t gb = (bRow + segB + lr) * 2048 + s0 + lc;
        gl_lds16(KThi + ga,               &Ah[buf][segA][0]);
        gl_lds16(KThi + ga + 16 * 2048,   &Ah[buf][segA + 16][0]);
        gl_lds16(KTlo + ga,               &Al[buf][segA][0]);
        gl_lds16(KTlo + ga + 16 * 2048,   &Al[buf][segA + 16][0]);
        gl_lds16(KzThi + gb,              &Bh[buf][segB][0]);
        gl_lds16(KzTlo + gb,              &Bl[buf][segB][0]);
    };

    stage(0, 0);
    __syncthreads();
    for (int c = 0; c < 16; ++c) {
        int buf = c & 1;
        if (c + 1 < 16) stage(buf ^ 1, c + 1);
        f16x8 fAh[4], fAl[4], fBh[2], fBl[2];
        #pragma unroll
        for (int i = 0; i < 4; ++i) {
            fAh[i] = *(f16x8*)&Ah[buf][wr + i * 16 + n][q * 8];
            fAl[i] = *(f16x8*)&Al[buf][wr + i * 16 + n][q * 8];
        }
        #pragma unroll
        for (int j = 0; j < 2; ++j) {
            fBh[j] = *(f16x8*)&Bh[buf][wc + j * 16 + n][q * 8];
            fBl[j] = *(f16x8*)&Bl[buf][wc + j * 16 + n][q * 8];
        }
        #pragma unroll
        for (int i = 0; i < 4; ++i)
            #pragma unroll
            for (int j = 0; j < 2; ++j) {
                acc[i][j] = __builtin_amdgcn_mfma_f32_16x16x32_f16(fAh[i], fBh[j], acc[i][j], 0, 0, 0);
                acc[i][j] = __builtin_amdgcn_mfma_f32_16x16x32_f16(fAh[i], fBl[j], acc[i][j], 0, 0, 0);
                acc[i][j] = __builtin_amdgcn_mfma_f32_16x16x32_f16(fAl[i], fBh[j], acc[i][j], 0, 0, 0);
            }
        __syncthreads();
    }
    float* dst = part + ((size_t)(split * DIMN + d)) * 1024 * 64;
    #pragma unroll
    for (int i = 0; i < 4; ++i)
        #pragma unroll
        for (int j = 0; j < 2; ++j)
            #pragma unroll
            for (int r = 0; r < 4; ++r) {
                int t = t0 + wr + i * 16 + q * 4 + r;
                dst[(size_t)t * 64 + wc + j * 16 + n] = acc[i][j][r];
            }
}

// ------ fused: sum Ktz partials + cho_solve + alpha splits + mean --------------------------
// RHS columns live in LDS (column-per-thread, stride 65 = conflict-free); rolled loops,
// no per-thread arrays -> no scratch spill (R5's solve spilled: VGPR=256, 72 MB scratch).
__global__ __launch_bounds__(64) void solve_kernel(const float* __restrict__ Lz,
                                                   const float* __restrict__ part2,
                                                   const float* __restrict__ dBz,
                                                   _Float16* __restrict__ aPhi,
                                                   _Float16* __restrict__ aPlo,
                                                   _Float16* __restrict__ aNhi,
                                                   _Float16* __restrict__ aNlo,
                                                   float* __restrict__ out0)
{
    int d = blockIdx.y;
    int t0 = blockIdx.x * 64;
    int i = threadIdx.x;
    __shared__ float L[64][65];
    __shared__ float bL[64][65];      // bL[m][col]
    __shared__ float inv[64];
    __shared__ float dB[64];
    for (int r = 0; r < 64; ++r)
        L[r][i] = Lz[(size_t)d * 4096 + (size_t)r * 64 + i];
    dB[i] = dBz[d * 64 + i];
    // sum 4 k-split partials; row r = t-col, thread i = m  (coalesced 64-float rows)
    for (int r = 0; r < 64; ++r) {
        size_t base = ((size_t)d * 1024 + t0 + r) * 64 + i;
        float s = part2[base] + part2[base + 524288] + part2[base + 1048576] + part2[base + 1572864];
        bL[i][r] = s;
    }
    __syncthreads();
    inv[i] = 1.f / L[i][i];
    __syncthreads();
    // in-place forward: thread i owns column i; L[j][k] lane-uniform (broadcast read)
    for (int j = 0; j < 64; ++j) {
        float s = bL[j][i];
        for (int k = 0; k < j; ++k) s -= L[j][k] * bL[k][i];
        bL[j][i] = s * inv[j];
    }
    // in-place backward
    for (int j = 63; j >= 0; --j) {
        float s = bL[j][i];
        for (int k = j + 1; k < 64; ++k) s -= L[k][j] * bL[k][i];
        bL[j][i] = s * inv[j];
    }
    // mean = dot(alpha_col, dBz)
    float mn = 0.f;
    for (int m = 0; m < 64; ++m) mn += bL[m][i] * dB[m];
    out0[d * 1024 + t0 + i] = mn;
    // emit fp16 hi/lo splits, [d][t][m], +/- variants
    size_t o = ((size_t)(d * 1024 + t0 + i)) * 64;
    for (int g = 0; g < 8; ++g) {
        union { _Float16 h[8]; float4 v; } ph, pl, nh, nl;
        #pragma unroll
        for (int k = 0; k < 8; ++k) {
            float x = bL[g * 8 + k][i];
            _Float16 h = (_Float16)x;
            _Float16 lo = (_Float16)(x - (float)h);
            ph.h[k] = h;  pl.h[k] = lo;
            nh.h[k] = -h; nl.h[k] = -lo;
        }
        *(float4*)&aPhi[o + g * 8] = ph.v;
        *(float4*)&aPlo[o + g * 8] = pl.v;
        *(float4*)&aNhi[o + g * 8] = nh.v;
        *(float4*)&aNlo[o + g * 8] = nl.v;
    }
}

// ---------------- var/std via MFMA; global_load_lds + double buffer ------------------------
__global__ __launch_bounds__(256, 2) void var_mfma_kernel(const _Float16* __restrict__ KThi,
                                                          const _Float16* __restrict__ KTlo,
                                                          const _Float16* __restrict__ aPhi,
                                                          const _Float16* __restrict__ aPlo,
                                                          const _Float16* __restrict__ aNhi,
                                                          const _Float16* __restrict__ aNlo,
                                                          float* __restrict__ out1)
{
    int tid = threadIdx.x;
    int wave = tid >> 6, lane = tid & 63;
    int n = lane & 15, q = lane >> 4;
    int lr = lane >> 2, lc = (lane & 3) * 8;
    int d = blockIdx.x;                 // fastest -> XCD locality
    int t0 = blockIdx.y * 128, u0 = blockIdx.z * 128;
    int wr = (wave >> 1) * 64, wc = (wave & 1) * 64;

    __shared__ _Float16 Ah[2][128][32], Al[2][128][32], Bh[2][128][32], Bl[2][128][32]; // 64 KB

    f32x4 acc[4][4];
    #pragma unroll
    for (int i = 0; i < 4; ++i)
        #pragma unroll
        for (int j = 0; j < 4; ++j) acc[i][j] = (f32x4)0.f;

    const size_t aRow = (size_t)(d * 1024 + t0);
    const size_t bRow = (size_t)(d * 1024 + u0);
    int segA = wave * 32;               // 32 rows per wave per tile (2 instrs per plane)

    auto stage = [&](int buf, int ck) {
        const _Float16 *ph, *pl, *qh, *ql;
        size_t str; int col;
        if (ck < 64) { ph = KThi; pl = KTlo; qh = KThi; ql = KTlo; str = 2048; col = ck * 32; }
        else         { ph = aPhi; pl = aPlo; qh = aNhi; ql = aNlo; str = 64;  col = (ck - 64) * 32; }
        size_t ga = (aRow + segA + lr) * str + col + lc;
        size_t gb = (bRow + segA + lr) * str + col + lc;
        gl_lds16(ph + ga,            &Ah[buf][segA][0]);
        gl_lds16(ph + ga + 16 * str, &Ah[buf][segA + 16][0]);
        gl_lds16(pl + ga,            &Al[buf][segA][0]);
        gl_lds16(pl + ga + 16 * str, &Al[buf][segA + 16][0]);
        gl_lds16(qh + gb,            &Bh[buf][segA][0]);
        gl_lds16(qh + gb + 16 * str, &Bh[buf][segA + 16][0]);
        gl_lds16(ql + gb,            &Bl[buf][segA][0]);
        gl_lds16(ql + gb + 16 * str, &Bl[buf][segA + 16][0]);
    };

    stage(0, 0);
    __syncthreads();
    for (int ck = 0; ck < 66; ++ck) {
        int buf = ck & 1;
        if (ck + 1 < 66) stage(buf ^ 1, ck + 1);   // DMA next chunk; overlaps MFMA below
        f16x8 fAh[4], fAl[4], fBh[4], fBl[4];
        #pragma unroll
        for (int i = 0; i < 4; ++i) {
            fAh[i] = *(f16x8*)&Ah[buf][wr + i * 16 + n][q * 8];
            fAl[i] = *(f16x8*)&Al[buf][wr + i * 16 + n][q * 8];
            fBh[i] = *(f16x8*)&Bh[buf][wc + i * 16 + n][q * 8];
            fBl[i] = *(f16x8*)&Bl[buf][wc + i * 16 + n][q * 8];
        }
        #pragma unroll
        for (int i = 0; i < 4; ++i)
            #pragma unroll
            for (int j = 0; j < 4; ++j) {
                acc[i][j] = __builtin_amdgcn_mfma_f32_16x16x32_f16(fAh[i], fBh[j], acc[i][j], 0, 0, 0);
                acc[i][j] = __builtin_amdgcn_mfma_f32_16x16x32_f16(fAh[i], fBl[j], acc[i][j], 0, 0, 0);
                acc[i][j] = __builtin_amdgcn_mfma_f32_16x16x32_f16(fAl[i], fBh[j], acc[i][j], 0, 0, 0);
            }
        __syncthreads();   // orders buf reuse; vmcnt drain here overlaps the work above
    }
    float* dst = out1 + ((size_t)d << 20);
    #pragma unroll
    for (int i = 0; i < 4; ++i)
        #pragma unroll
        for (int j = 0; j < 4; ++j)
            #pragma unroll
            for (int r = 0; r < 4; ++r) {
                int t = t0 + wr + i * 16 + q * 4 + r;
                int u = u0 + wc + j * 16 + n;
                float v = acc[i][j][r];
                dst[(size_t)t * 1024 + u] = sqrtf(fmaxf(v, 1e-12f)) * SQRTDT_F;
            }
}

extern "C" void kernel_launch(void* const* d_in, const int* in_sizes, int n_in,
                              void* d_out, int out_size, void* d_ws, size_t ws_size,
                              hipStream_t stream)
{
    const float* t_in  = (const float*)d_in[0];
    const float* y0    = (const float*)d_in[1];
    const float* eps_z = (const float*)d_in[2];
    const float* W1    = (const float*)d_in[3];
    const float* b1    = (const float*)d_in[4];
    const float* W2    = (const float*)d_in[5];
    const float* b2    = (const float*)d_in[6];
    const float* Wc1   = (const float*)d_in[7];
    const float* bc1   = (const float*)d_in[8];
    const float* Wc2   = (const float*)d_in[9];
    const float* bc2   = (const float*)d_in[10];
    const float* dw    = (const float*)d_in[11];
    const float* cw    = (const float*)d_in[12];

    float* ws = (float*)d_ws;
    size_t off = 0;
    auto carve = [&](size_t n) { float* p = ws + off; off += n; return p; };
    float* coef_t   = carve(32768);
    float* coef_z   = carve(2048);
    float* times_z  = carve(64);
    float* Kzz      = carve(32768);
    float* Lz       = carve(32768);
    float* dBz      = carve(512);
    float* Kz       = carve(1048576);
    _Float16* KThi  = (_Float16*)carve(8388608);
    _Float16* KTlo  = (_Float16*)carve(8388608);
    _Float16* KzThi = (_Float16*)carve(524288);
    _Float16* KzTlo = (_Float16*)carve(524288);
    float* part1    = carve(262144);
    float* part2    = carve(2097152);
    _Float16* aPhi  = (_Float16*)carve(262144);
    _Float16* aPlo  = (_Float16*)carve(262144);
    _Float16* aNhi  = (_Float16*)carve(262144);
    _Float16* aNlo  = (_Float16*)carve(262144);

    float* out0 = (float*)d_out;
    float* out1 = out0 + (size_t)DIMN * 1024;

    coef_kernel<<<9, 128, 0, stream>>>(t_in, y0, W1, b1, W2, b2, Wc1, bc1, Wc2, bc2, dw, cw,
                                       (float4*)coef_t, (float4*)coef_z, times_z);
    kmat_t_kernel<<<dim3(32, 32, 8), 256, 0, stream>>>(t_in, (const float4*)coef_t,
                                                       KThi, KTlo);
    kmat_z_kernel<<<dim3(2, 32, 8), 256, 0, stream>>>(times_z, (const float4*)coef_z,
                                                      Kz, KzThi, KzTlo);
    kzz_partial_kernel<<<dim3(8, 8), 256, 0, stream>>>(Kz, part1);
    reduce_kernel<<<128, 256, 0, stream>>>(part1, Kzz, 32768, 8);
    chol_kernel<<<8, 64, 0, stream>>>(Kzz, eps_z, Lz, dBz);
    ktz_mfma_kernel<<<dim3(8, 8, 4), 256, 0, stream>>>(KThi, KTlo, KzThi, KzTlo, part2);
    solve_kernel<<<dim3(16, 8), 64, 0, stream>>>(Lz, part2, dBz, aPhi, aPlo, aNhi, aNlo, out0);
    var_mfma_kernel<<<dim3(8, 8, 8), 256, 0, stream>>>(KThi, KTlo, aPhi, aPlo, aNhi, aNlo, out1);
}